// Round 3
// baseline (172.840 us; speedup 1.0000x reference)
//
#include <hip/hip_runtime.h>
#include <hip/hip_bf16.h>
#include <stdint.h>

#define H 512
#define F 2048
#define E 8
#define NTOK 8192

typedef __bf16 bf16x8 __attribute__((ext_vector_type(8)));
typedef float f32x4 __attribute__((ext_vector_type(4)));

__device__ __forceinline__ unsigned short f2bf(float f) {
    unsigned u = __builtin_bit_cast(unsigned, f);
    u += 0x7FFFu + ((u >> 16) & 1u);
    return (unsigned short)(u >> 16);
}

__device__ __forceinline__ void gl_lds16(const unsigned short* g, unsigned short* l) {
    __builtin_amdgcn_global_load_lds(
        (const __attribute__((address_space(1))) unsigned int*)g,
        (__attribute__((address_space(3))) unsigned int*)l,
        16, 0, 0);
}

// ---------- x fp32 -> bf16 ----------
__global__ void cvt_x_kernel(const float* __restrict__ x, unsigned short* __restrict__ xbf) {
    int i = blockIdx.x * blockDim.x + threadIdx.x;
    const float4* x4 = (const float4*)x;
    float4 a = x4[i * 2], b = x4[i * 2 + 1];
    uint4 u;
    u.x = (unsigned)f2bf(a.x) | ((unsigned)f2bf(a.y) << 16);
    u.y = (unsigned)f2bf(a.z) | ((unsigned)f2bf(a.w) << 16);
    u.z = (unsigned)f2bf(b.x) | ((unsigned)f2bf(b.y) << 16);
    u.w = (unsigned)f2bf(b.z) | ((unsigned)f2bf(b.w) << 16);
    ((uint4*)xbf)[i] = u;
}

// ---------- transpose + convert: src [b][R][C] fp32 -> dst [b][C][R] bf16 ----------
__global__ void transpose_cvt_kernel(const float* __restrict__ src, unsigned short* __restrict__ dst,
                                     int R, int C) {
    __shared__ unsigned short t[64][72];
    const float* s = src + (size_t)blockIdx.z * R * C;
    unsigned short* d = dst + (size_t)blockIdx.z * R * C;
    int r0 = blockIdx.y * 64, c0 = blockIdx.x * 64;
    int tid = threadIdx.x;
    int lrow = tid >> 4, lc4 = (tid & 15) * 4;
    #pragma unroll
    for (int p = 0; p < 4; ++p) {
        int r = p * 16 + lrow;
        float4 v = *(const float4*)(s + (size_t)(r0 + r) * C + c0 + lc4);
        unsigned short* tp = &t[r][lc4];
        uint2 u;
        u.x = (unsigned)f2bf(v.x) | ((unsigned)f2bf(v.y) << 16);
        u.y = (unsigned)f2bf(v.z) | ((unsigned)f2bf(v.w) << 16);
        *(uint2*)tp = u;
    }
    __syncthreads();
    int och = tid & 7;
    #pragma unroll
    for (int q = 0; q < 2; ++q) {
        int orow = q * 32 + (tid >> 3);
        unsigned short u[8];
        #pragma unroll
        for (int si = 0; si < 8; ++si) u[si] = t[och * 8 + si][orow];
        uint4 uv;
        uv.x = (unsigned)u[0] | ((unsigned)u[1] << 16);
        uv.y = (unsigned)u[2] | ((unsigned)u[3] << 16);
        uv.z = (unsigned)u[4] | ((unsigned)u[5] << 16);
        uv.w = (unsigned)u[6] | ((unsigned)u[7] << 16);
        *(uint4*)(d + (size_t)(c0 + orow) * R + r0 + och * 8) = uv;
    }
}

// ---------- router ----------
__global__ void router_kernel(const float* __restrict__ x, const float* __restrict__ Wg,
                              float* __restrict__ gate, int* __restrict__ list,
                              int* __restrict__ cnt, float* __restrict__ pprob) {
    __shared__ float wg[H * E];
    __shared__ float lg[32][8];
    __shared__ int am_l[32];
    __shared__ int rank_l[32];
    __shared__ int eb[8];
    int tid = threadIdx.x;

    #pragma unroll
    for (int p = 0; p < 16; ++p) wg[p * 256 + tid] = Wg[p * 256 + tid];
    __syncthreads();

    int tl = tid >> 3, e = tid & 7;
    int token = blockIdx.x * 32 + tl;
    const float4* x4 = (const float4*)(x + (size_t)token * H);
    float acc = 0.f;
    for (int kq = 0; kq < 128; ++kq) {
        float4 v = x4[kq];
        acc += v.x * wg[(kq * 4 + 0) * 8 + e];
        acc += v.y * wg[(kq * 4 + 1) * 8 + e];
        acc += v.z * wg[(kq * 4 + 2) * 8 + e];
        acc += v.w * wg[(kq * 4 + 3) * 8 + e];
    }
    lg[tl][e] = acc;
    __syncthreads();

    if (tid < 32) {
        float l[8];
        #pragma unroll
        for (int q = 0; q < 8; ++q) l[q] = lg[tid][q];
        float mx = l[0];
        #pragma unroll
        for (int q = 1; q < 8; ++q) mx = fmaxf(mx, l[q]);
        float p[8]; float s = 0.f;
        #pragma unroll
        for (int q = 0; q < 8; ++q) { p[q] = expf(l[q] - mx); s += p[q]; }
        int am = 0; float best = l[0];
        #pragma unroll
        for (int q = 1; q < 8; ++q) if (l[q] > best) { best = l[q]; am = q; }
        float inv = 1.f / s;
        #pragma unroll
        for (int q = 0; q < 8; ++q) lg[tid][q] = p[q] * inv;
        float sp = p[am] * inv;
        gate[blockIdx.x * 32 + tid] = sp / (sp + 1e-8f);
        am_l[tid] = am;
    }
    __syncthreads();

    if (tid < 8) {
        float s = 0.f;
        for (int i = 0; i < 32; ++i) s += lg[i][tid];
        pprob[blockIdx.x * 8 + tid] = s;
        int c = 0;
        for (int i = 0; i < 32; ++i) if (am_l[i] == tid) rank_l[i] = c++;
        eb[tid] = atomicAdd(&cnt[tid], c);
    }
    __syncthreads();

    if (tid < 32) {
        int e2 = am_l[tid];
        list[e2 * NTOK + eb[e2] + rank_l[tid]] = blockIdx.x * 32 + tid;
    }
}

// ---------- plan: per-expert counts -> compact work lists ----------
__global__ void plan_kernel(const int* __restrict__ cnt, int* __restrict__ work1,
                            int* __restrict__ work2, int* __restrict__ nwork) {
    if (threadIdx.x == 0) {
        int n1 = 0, n2 = 0;
        for (int e = 0; e < E; ++e) {
            int c = cnt[e];
            for (int m = 0; m * 128 < c; ++m) work1[n1++] = (e << 16) | m;
            for (int m = 0; m * 64 < c; ++m)  work2[n2++] = (e << 16) | m;
        }
        nwork[0] = n1; nwork[1] = n2;
    }
}

// ---------- GEMM1: h = relu(x_g @ W1t^T + b1), BM=128 BN=128 BK=64, 2-ph pipeline ----------
__global__ __launch_bounds__(256, 2) void gemm1_kernel(
    const unsigned short* __restrict__ xbf,   // [NTOK][H]
    const unsigned short* __restrict__ w1t,   // [E][F][H]
    const float* __restrict__ b1,
    const int* __restrict__ list, const int* __restrict__ cnt,
    const int* __restrict__ work1, const int* __restrict__ nwork,
    unsigned short* __restrict__ hbf)         // [NTOK][F]
{
    int bid = blockIdx.y * 16 + blockIdx.x;
    int xcd = bid & 7, j = bid >> 3;
    int wi = xcd + 8 * (j >> 4);              // work index: same-work n-blocks share XCD
    int n0 = (j & 15) * 128;
    if (wi >= nwork[0]) return;
    int wk = work1[wi];
    int e = wk >> 16;
    int m0 = (wk & 0xffff) * 128;
    int count = cnt[e];

    __shared__ unsigned short Al[2][128 * 64];   // 2 x 16 KB
    __shared__ unsigned short Bl[2][128 * 64];   // 2 x 16 KB
    __shared__ int toks[128];
    int tid = threadIdx.x;
    if (tid < 128) {
        int m = m0 + tid;
        toks[tid] = (m < count) ? list[e * NTOK + m] : -1;
    }
    __syncthreads();

    int lane = tid & 63, w = tid >> 6;
    int lr8 = lane >> 3, lch = lane & 7;

    const unsigned short* asrc[4];
    const unsigned short* bsrc[4];
    #pragma unroll
    for (int i = 0; i < 4; ++i) {
        int seg = w * 4 + i;
        int row = seg * 8 + lr8;
        int tk = toks[row]; int tkc = tk < 0 ? 0 : tk;
        asrc[i] = xbf + (size_t)tkc * H + lch * 8;
        bsrc[i] = w1t + ((size_t)e * F + n0 + row) * H + lch * 8;
    }

    f32x4 acc[4][4] = {};
    int mb = (w >> 1) * 64, nb = (w & 1) * 64;
    int lr = lane & 15, lkb = (lane >> 4) * 8;

    // prologue: stage tile 0 into buf 0
    #pragma unroll
    for (int i = 0; i < 4; ++i) {
        int seg = w * 4 + i;
        gl_lds16(asrc[i], &Al[0][seg * 512]);
        gl_lds16(bsrc[i], &Bl[0][seg * 512]);
    }
    __syncthreads();

    const int NT = H / 64;  // 8
    int cur = 0;
    for (int t = 0; t < NT; ++t) {
        if (t + 1 < NT) {
            int k0 = (t + 1) * 64;
            #pragma unroll
            for (int i = 0; i < 4; ++i) {
                int seg = w * 4 + i;
                gl_lds16(asrc[i] + k0, &Al[cur ^ 1][seg * 512]);
                gl_lds16(bsrc[i] + k0, &Bl[cur ^ 1][seg * 512]);
            }
        }
        #pragma unroll
        for (int kk = 0; kk < 2; ++kk) {
            bf16x8 a[4], b[4];
            #pragma unroll
            for (int i = 0; i < 4; ++i)
                a[i] = *(const bf16x8*)(&Al[cur][(mb + i * 16 + lr) * 64 + kk * 32 + lkb]);
            #pragma unroll
            for (int jj = 0; jj < 4; ++jj)
                b[jj] = *(const bf16x8*)(&Bl[cur][(nb + jj * 16 + lr) * 64 + kk * 32 + lkb]);
            #pragma unroll
            for (int i = 0; i < 4; ++i)
                #pragma unroll
                for (int jj = 0; jj < 4; ++jj)
                    acc[i][jj] = __builtin_amdgcn_mfma_f32_16x16x32_bf16(a[i], b[jj], acc[i][jj], 0, 0, 0);
        }
        __syncthreads();   // drains this iter's prefetch vmcnt + barrier
        cur ^= 1;
    }

    int rbase = (lane >> 4) * 4;
    #pragma unroll
    for (int jj = 0; jj < 4; ++jj) {
        int gcol = n0 + nb + jj * 16 + lr;
        float bias = b1[e * F + gcol];
        #pragma unroll
        for (int i = 0; i < 4; ++i) {
            #pragma unroll
            for (int r = 0; r < 4; ++r) {
                int rl = mb + i * 16 + rbase + r;
                int tk = toks[rl];
                if (tk >= 0) {
                    float v = acc[i][jj][r] + bias;
                    v = v > 0.f ? v : 0.f;
                    hbf[(size_t)tk * F + gcol] = f2bf(v);
                }
            }
        }
    }
}

// ---------- GEMM2: out = gate * (h_g @ W2t^T + b2), BM=64 BN=128 BK=64, 2-ph pipeline ----------
__global__ __launch_bounds__(256, 3) void gemm2_kernel(
    const unsigned short* __restrict__ hbf,   // [NTOK][F]
    const unsigned short* __restrict__ w2t,   // [E][H][F]
    const float* __restrict__ b2,
    const int* __restrict__ list, const int* __restrict__ cnt,
    const int* __restrict__ work2, const int* __restrict__ nwork,
    const float* __restrict__ gate,
    float* __restrict__ out)                  // [NTOK][H]
{
    int bid = blockIdx.y * 4 + blockIdx.x;
    int xcd = bid & 7, j = bid >> 3;
    int wi = xcd + 8 * (j >> 2);              // same-work n-blocks share XCD
    int n0 = (j & 3) * 128;
    if (wi >= nwork[1]) return;
    int wk = work2[wi];
    int e = wk >> 16;
    int m0 = (wk & 0xffff) * 64;
    int count = cnt[e];

    __shared__ unsigned short Al[2][64 * 64];    // 2 x 8 KB
    __shared__ unsigned short Bl[2][128 * 64];   // 2 x 16 KB
    __shared__ int toks[64];
    __shared__ float gts[64];
    int tid = threadIdx.x;
    if (tid < 64) {
        int m = m0 + tid;
        int tk = (m < count) ? list[e * NTOK + m] : -1;
        toks[tid] = tk;
        gts[tid] = (tk >= 0) ? gate[tk] : 0.f;
    }
    __syncthreads();

    int lane = tid & 63, w = tid >> 6;
    int lr8 = lane >> 3, lch = lane & 7;

    const unsigned short* asrc[2];
    const unsigned short* bsrc[4];
    #pragma unroll
    for (int i = 0; i < 2; ++i) {
        int seg = w * 2 + i;
        int row = seg * 8 + lr8;
        int tk = toks[row]; int tkc = tk < 0 ? 0 : tk;
        asrc[i] = hbf + (size_t)tkc * F + lch * 8;
    }
    #pragma unroll
    for (int i = 0; i < 4; ++i) {
        int seg = w * 4 + i;
        int row = seg * 8 + lr8;
        bsrc[i] = w2t + ((size_t)e * H + n0 + row) * F + lch * 8;
    }

    f32x4 acc[2][4] = {};
    int mb = (w >> 1) * 32, nb = (w & 1) * 64;
    int lr = lane & 15, lkb = (lane >> 4) * 8;

    // prologue
    #pragma unroll
    for (int i = 0; i < 2; ++i) gl_lds16(asrc[i], &Al[0][(w * 2 + i) * 512]);
    #pragma unroll
    for (int i = 0; i < 4; ++i) gl_lds16(bsrc[i], &Bl[0][(w * 4 + i) * 512]);
    __syncthreads();

    const int NT = F / 64;  // 32
    int cur = 0;
    for (int t = 0; t < NT; ++t) {
        if (t + 1 < NT) {
            int k0 = (t + 1) * 64;
            #pragma unroll
            for (int i = 0; i < 2; ++i) gl_lds16(asrc[i] + k0, &Al[cur ^ 1][(w * 2 + i) * 512]);
            #pragma unroll
            for (int i = 0; i < 4; ++i) gl_lds16(bsrc[i] + k0, &Bl[cur ^ 1][(w * 4 + i) * 512]);
        }
        #pragma unroll
        for (int kk = 0; kk < 2; ++kk) {
            bf16x8 a[2], b[4];
            #pragma unroll
            for (int i = 0; i < 2; ++i)
                a[i] = *(const bf16x8*)(&Al[cur][(mb + i * 16 + lr) * 64 + kk * 32 + lkb]);
            #pragma unroll
            for (int jj = 0; jj < 4; ++jj)
                b[jj] = *(const bf16x8*)(&Bl[cur][(nb + jj * 16 + lr) * 64 + kk * 32 + lkb]);
            #pragma unroll
            for (int i = 0; i < 2; ++i)
                #pragma unroll
                for (int jj = 0; jj < 4; ++jj)
                    acc[i][jj] = __builtin_amdgcn_mfma_f32_16x16x32_bf16(a[i], b[jj], acc[i][jj], 0, 0, 0);
        }
        __syncthreads();
        cur ^= 1;
    }

    int rbase = (lane >> 4) * 4;
    #pragma unroll
    for (int jj = 0; jj < 4; ++jj) {
        int gcol = n0 + nb + jj * 16 + lr;
        float bias = b2[e * H + gcol];
        #pragma unroll
        for (int i = 0; i < 2; ++i) {
            #pragma unroll
            for (int r = 0; r < 4; ++r) {
                int rl = mb + i * 16 + rbase + r;
                int tk = toks[rl];
                if (tk >= 0) {
                    out[(size_t)tk * H + gcol] = gts[rl] * (acc[i][jj][r] + bias);
                }
            }
        }
    }
}

// ---------- lb loss ----------
__global__ void lb_kernel(const float* __restrict__ pprob, const int* __restrict__ cnt,
                          float* __restrict__ outlb) {
    __shared__ float s[8];
    int t = threadIdx.x;
    if (t < 8) {
        float acc = 0.f;
        for (int i = 0; i < 256; ++i) acc += pprob[i * 8 + t];
        s[t] = acc * (float)cnt[t];
    }
    __syncthreads();
    if (t == 0) {
        float tot = 0.f;
        for (int q = 0; q < 8; ++q) tot += s[q];
        outlb[0] = tot * (8.0f / ((float)NTOK * (float)NTOK));
    }
}

extern "C" void kernel_launch(void* const* d_in, const int* in_sizes, int n_in,
                              void* d_out, int out_size, void* d_ws, size_t ws_size,
                              hipStream_t stream) {
    const float* x  = (const float*)d_in[0];
    const float* Wg = (const float*)d_in[1];
    const float* W1 = (const float*)d_in[2];
    const float* b1 = (const float*)d_in[3];
    const float* W2 = (const float*)d_in[4];
    const float* b2 = (const float*)d_in[5];
    float* out = (float*)d_out;

    char* ws = (char*)d_ws;
    unsigned short* xbf = (unsigned short*)(ws + 0);          //  8 MB
    unsigned short* w1t = (unsigned short*)(ws + 8388608);    // 16 MB
    unsigned short* w2t = (unsigned short*)(ws + 25165824);   // 16 MB
    unsigned short* hbf = (unsigned short*)(ws + 41943040);   // 32 MB
    float* gate = (float*)(ws + 75497472);                    // 32 KB
    int* list   = (int*)(ws + 75530240);                      // 256 KB
    int* cnt    = (int*)(ws + 75792384);                      // 32 B
    float* pprob= (float*)(ws + 75792448);                    // 8 KB
    int* work1  = (int*)(ws + 75800640);                      // 288 B
    int* work2  = (int*)(ws + 75801088);                      // 544 B
    int* nwork  = (int*)(ws + 75801728);                      // 8 B

    hipMemsetAsync(cnt, 0, 8 * sizeof(int), stream);
    cvt_x_kernel<<<2048, 256, 0, stream>>>(x, xbf);
    transpose_cvt_kernel<<<dim3(32, 8, 8), 256, 0, stream>>>(W1, w1t, 512, 2048);
    transpose_cvt_kernel<<<dim3(8, 32, 8), 256, 0, stream>>>(W2, w2t, 2048, 512);
    router_kernel<<<256, 256, 0, stream>>>(x, Wg, gate, list, cnt, pprob);
    plan_kernel<<<1, 64, 0, stream>>>(cnt, work1, work2, nwork);
    gemm1_kernel<<<dim3(16, 72), 256, 0, stream>>>(xbf, w1t, b1, list, cnt, work1, nwork, hbf);
    gemm2_kernel<<<dim3(4, 136), 256, 0, stream>>>(hbf, w2t, b2, list, cnt, work2, nwork, gate, out);
    lb_kernel<<<1, 64, 0, stream>>>(pprob, cnt, out + (size_t)NTOK * H);
}

// Round 4
// 138.198 us; speedup vs baseline: 1.2507x; 1.2507x over previous
//
#include <hip/hip_runtime.h>
#include <hip/hip_bf16.h>
#include <stdint.h>

#define H 512
#define F 2048
#define E 8
#define NTOK 8192
#define LSTRIDE 4096

typedef __bf16 bf16x8 __attribute__((ext_vector_type(8)));
typedef float f32x4 __attribute__((ext_vector_type(4)));

__device__ __forceinline__ unsigned short f2bf(float f) {
    unsigned u = __builtin_bit_cast(unsigned, f);
    u += 0x7FFFu + ((u >> 16) & 1u);
    return (unsigned short)(u >> 16);
}

__device__ __forceinline__ void gl_lds16(const unsigned short* g, unsigned short* l) {
    __builtin_amdgcn_global_load_lds(
        (const __attribute__((address_space(1))) unsigned int*)g,
        (__attribute__((address_space(3))) unsigned int*)l,
        16, 0, 0);
}

// ---------- transpose + convert: src [b][R][C] fp32 -> dst [b][C][R] bf16 ----------
__global__ void transpose_cvt_kernel(const float* __restrict__ src, unsigned short* __restrict__ dst,
                                     int R, int C) {
    __shared__ unsigned short t[64][72];
    const float* s = src + (size_t)blockIdx.z * R * C;
    unsigned short* d = dst + (size_t)blockIdx.z * R * C;
    int r0 = blockIdx.y * 64, c0 = blockIdx.x * 64;
    int tid = threadIdx.x;
    int lrow = tid >> 4, lc4 = (tid & 15) * 4;
    #pragma unroll
    for (int p = 0; p < 4; ++p) {
        int r = p * 16 + lrow;
        float4 v = *(const float4*)(s + (size_t)(r0 + r) * C + c0 + lc4);
        uint2 u;
        u.x = (unsigned)f2bf(v.x) | ((unsigned)f2bf(v.y) << 16);
        u.y = (unsigned)f2bf(v.z) | ((unsigned)f2bf(v.w) << 16);
        *(uint2*)(&t[r][lc4]) = u;
    }
    __syncthreads();
    int och = tid & 7;
    #pragma unroll
    for (int q = 0; q < 2; ++q) {
        int orow = q * 32 + (tid >> 3);
        unsigned short u[8];
        #pragma unroll
        for (int si = 0; si < 8; ++si) u[si] = t[och * 8 + si][orow];
        uint4 uv;
        uv.x = (unsigned)u[0] | ((unsigned)u[1] << 16);
        uv.y = (unsigned)u[2] | ((unsigned)u[3] << 16);
        uv.z = (unsigned)u[4] | ((unsigned)u[5] << 16);
        uv.w = (unsigned)u[6] | ((unsigned)u[7] << 16);
        *(uint4*)(d + (size_t)(c0 + orow) * R + r0 + och * 8) = uv;
    }
}

// ---------- router ----------
__global__ void router_kernel(const float* __restrict__ x, const float* __restrict__ Wg,
                              float* __restrict__ gate, int* __restrict__ list,
                              int* __restrict__ cnt, float* __restrict__ pprob) {
    __shared__ float wg[H * E];
    __shared__ float lg[32][8];
    __shared__ int am_l[32];
    __shared__ int rank_l[32];
    __shared__ int eb[8];
    int tid = threadIdx.x;

    #pragma unroll
    for (int p = 0; p < 16; ++p) wg[p * 256 + tid] = Wg[p * 256 + tid];
    __syncthreads();

    int tl = tid >> 3, e = tid & 7;
    int token = blockIdx.x * 32 + tl;
    const float4* x4 = (const float4*)(x + (size_t)token * H);
    float acc = 0.f;
    for (int kq = 0; kq < 128; ++kq) {
        float4 v = x4[kq];
        acc += v.x * wg[(kq * 4 + 0) * 8 + e];
        acc += v.y * wg[(kq * 4 + 1) * 8 + e];
        acc += v.z * wg[(kq * 4 + 2) * 8 + e];
        acc += v.w * wg[(kq * 4 + 3) * 8 + e];
    }
    lg[tl][e] = acc;
    __syncthreads();

    if (tid < 32) {
        float l[8];
        #pragma unroll
        for (int q = 0; q < 8; ++q) l[q] = lg[tid][q];
        float mx = l[0];
        #pragma unroll
        for (int q = 1; q < 8; ++q) mx = fmaxf(mx, l[q]);
        float p[8]; float s = 0.f;
        #pragma unroll
        for (int q = 0; q < 8; ++q) { p[q] = expf(l[q] - mx); s += p[q]; }
        int am = 0; float best = l[0];
        #pragma unroll
        for (int q = 1; q < 8; ++q) if (l[q] > best) { best = l[q]; am = q; }
        float inv = 1.f / s;
        #pragma unroll
        for (int q = 0; q < 8; ++q) lg[tid][q] = p[q] * inv;
        float sp = p[am] * inv;
        gate[blockIdx.x * 32 + tid] = sp / (sp + 1e-8f);
        am_l[tid] = am;
    }
    __syncthreads();

    if (tid < 8) {
        float s = 0.f;
        for (int i = 0; i < 32; ++i) s += lg[i][tid];
        pprob[blockIdx.x * 8 + tid] = s;
        int c = 0;
        for (int i = 0; i < 32; ++i) if (am_l[i] == tid) rank_l[i] = c++;
        eb[tid] = atomicAdd(&cnt[tid], c);
    }
    __syncthreads();

    if (tid < 32) {
        int e2 = am_l[tid];
        int pos = eb[e2] + rank_l[tid];
        if (pos < LSTRIDE) list[e2 * LSTRIDE + pos] = blockIdx.x * 32 + tid;
    }
}

// ---------- plan (prefix + work lists) fused with lb loss ----------
__global__ void plan_kernel(const int* __restrict__ cnt, const float* __restrict__ pprob,
                            int* __restrict__ ebase, int* __restrict__ work1,
                            int* __restrict__ work2, int* __restrict__ nwork,
                            float* __restrict__ outlb) {
    __shared__ float s[8];
    int t = threadIdx.x;
    if (t < 8) {
        float acc = 0.f;
        for (int i = 0; i < 256; ++i) acc += pprob[i * 8 + t];
        s[t] = acc * (float)cnt[t];
    }
    __syncthreads();
    if (t == 0) {
        float tot = 0.f;
        for (int q = 0; q < 8; ++q) tot += s[q];
        outlb[0] = tot * (8.0f / ((float)NTOK * (float)NTOK));
        int b = 0, n1 = 0, n2 = 0;
        for (int e = 0; e < E; ++e) {
            ebase[e] = b;
            int c = cnt[e];
            for (int m = 0; m * 128 < c; ++m) work1[n1++] = (e << 16) | m;
            for (int m = 0; m * 64 < c; ++m)  work2[n2++] = (e << 16) | m;
            b += c;
        }
        nwork[0] = n1; nwork[1] = n2;
    }
}

// ---------- gather: x (fp32, token order) -> xg (bf16, expert-sorted) + gs/stok ----------
__global__ void gather_kernel(const float* __restrict__ x, const float* __restrict__ gate,
                              const int* __restrict__ list, const int* __restrict__ ebase,
                              unsigned short* __restrict__ xg, float* __restrict__ gs,
                              int* __restrict__ stok) {
    int p = blockIdx.x * 4 + (threadIdx.x >> 6);
    int lane = threadIdx.x & 63;
    int e = 0;
    #pragma unroll
    for (int q = 1; q < 8; ++q) if (p >= ebase[q]) e = q;
    int token = list[e * LSTRIDE + (p - ebase[e])];
    const float4* src = (const float4*)(x + (size_t)token * H) + lane * 2;
    float4 a = src[0], b = src[1];
    uint4 u;
    u.x = (unsigned)f2bf(a.x) | ((unsigned)f2bf(a.y) << 16);
    u.y = (unsigned)f2bf(a.z) | ((unsigned)f2bf(a.w) << 16);
    u.z = (unsigned)f2bf(b.x) | ((unsigned)f2bf(b.y) << 16);
    u.w = (unsigned)f2bf(b.z) | ((unsigned)f2bf(b.w) << 16);
    *(uint4*)(xg + (size_t)p * H + lane * 8) = u;
    if (lane == 0) { stok[p] = token; gs[p] = gate[token]; }
}

// ---------- GEMM1: dense sorted, h = relu(xg @ W1t^T + b1), 128x128xBK64 single-buf ----------
__global__ __launch_bounds__(256, 3) void gemm1_kernel(
    const unsigned short* __restrict__ xg,    // [NTOK][H] sorted
    const unsigned short* __restrict__ w1t,   // [E][F][H]
    const float* __restrict__ b1,
    const int* __restrict__ ebase, const int* __restrict__ cnt,
    const int* __restrict__ work1, const int* __restrict__ nwork,
    unsigned short* __restrict__ hbf)         // [NTOK][F] sorted
{
    int wi = blockIdx.y;
    if (wi >= nwork[0]) return;
    int wk = work1[wi];
    int e = wk >> 16, mblk = wk & 0xffff;
    int m0 = ebase[e] + mblk * 128;
    int segEnd = ebase[e] + cnt[e];
    int n0 = blockIdx.x * 128;

    __shared__ unsigned short Al[128 * 64];   // 16 KB linear
    __shared__ unsigned short Bl[128 * 64];   // 16 KB

    int tid = threadIdx.x, lane = tid & 63, w = tid >> 6;
    int lr8 = lane >> 3, lch = lane & 7;
    int swc = lch ^ lr8;                       // source-side chunk swizzle

    const unsigned short* asrc[4];
    const unsigned short* bsrc[4];
    #pragma unroll
    for (int i = 0; i < 4; ++i) {
        int seg = w * 4 + i;
        int row = seg * 8 + lr8;
        int ar = m0 + row; if (ar > NTOK - 1) ar = NTOK - 1;
        asrc[i] = xg + (size_t)ar * H + swc * 8;
        bsrc[i] = w1t + ((size_t)e * F + n0 + row) * H + swc * 8;
    }

    f32x4 acc[4][4] = {};
    int mb = (w >> 1) * 64, nb = (w & 1) * 64;
    int lr = lane & 15, x16 = lane >> 4;
    int sw = (lr & 7) << 4;                    // read-side byte XOR

    for (int t = 0; t < 8; ++t) {
        int k0 = t * 64;
        #pragma unroll
        for (int i = 0; i < 4; ++i) {
            int seg = w * 4 + i;
            gl_lds16(asrc[i] + k0, &Al[seg * 512]);
            gl_lds16(bsrc[i] + k0, &Bl[seg * 512]);
        }
        __syncthreads();
        #pragma unroll
        for (int kk = 0; kk < 2; ++kk) {
            int co = (kk * 64 + x16 * 16) ^ sw;
            bf16x8 a[4], b[4];
            #pragma unroll
            for (int i = 0; i < 4; ++i)
                a[i] = *(const bf16x8*)((const char*)Al + (mb + i * 16 + lr) * 128 + co);
            #pragma unroll
            for (int j = 0; j < 4; ++j)
                b[j] = *(const bf16x8*)((const char*)Bl + (nb + j * 16 + lr) * 128 + co);
            #pragma unroll
            for (int i = 0; i < 4; ++i)
                #pragma unroll
                for (int j = 0; j < 4; ++j)
                    acc[i][j] = __builtin_amdgcn_mfma_f32_16x16x32_bf16(a[i], b[j], acc[i][j], 0, 0, 0);
        }
        __syncthreads();
    }

    int rbase = x16 * 4;
    #pragma unroll
    for (int j = 0; j < 4; ++j) {
        int gcol = n0 + nb + j * 16 + lr;
        float bias = b1[e * F + gcol];
        #pragma unroll
        for (int i = 0; i < 4; ++i) {
            #pragma unroll
            for (int r = 0; r < 4; ++r) {
                int p = m0 + mb + i * 16 + rbase + r;
                if (p < segEnd) {
                    float v = acc[i][j][r] + bias;
                    v = v > 0.f ? v : 0.f;
                    hbf[(size_t)p * F + gcol] = f2bf(v);
                }
            }
        }
    }
}

// ---------- GEMM2: dense sorted, out = gate*(h @ W2t^T + b2) scattered, 64x128xBK64 dbuf ----------
__global__ __launch_bounds__(256, 2) void gemm2_kernel(
    const unsigned short* __restrict__ hbf,   // [NTOK][F] sorted
    const unsigned short* __restrict__ w2t,   // [E][H][F]
    const float* __restrict__ b2,
    const int* __restrict__ ebase, const int* __restrict__ cnt,
    const int* __restrict__ work2, const int* __restrict__ nwork,
    const float* __restrict__ gs, const int* __restrict__ stok,
    float* __restrict__ out)                  // [NTOK][H] token order
{
    int wi = blockIdx.y;
    if (wi >= nwork[1]) return;
    int wk = work2[wi];
    int e = wk >> 16, mblk = wk & 0xffff;
    int m0 = ebase[e] + mblk * 64;
    int segEnd = ebase[e] + cnt[e];
    int n0 = blockIdx.x * 128;

    __shared__ unsigned short Al[2][64 * 64];    // 2 x 8 KB
    __shared__ unsigned short Bl[2][128 * 64];   // 2 x 16 KB
    __shared__ int stokL[64];
    __shared__ float gsL[64];

    int tid = threadIdx.x, lane = tid & 63, w = tid >> 6;
    if (tid < 64) {
        int p = m0 + tid;
        int pc = p > NTOK - 1 ? NTOK - 1 : p;
        stokL[tid] = stok[pc];
        gsL[tid] = gs[pc];
    }
    int lr8 = lane >> 3, lch = lane & 7;
    int swc = lch ^ lr8;

    const unsigned short* asrc[2];
    const unsigned short* bsrc[4];
    #pragma unroll
    for (int i = 0; i < 2; ++i) {
        int seg = w * 2 + i;
        int row = seg * 8 + lr8;
        int ar = m0 + row; if (ar > NTOK - 1) ar = NTOK - 1;
        asrc[i] = hbf + (size_t)ar * F + swc * 8;
    }
    #pragma unroll
    for (int i = 0; i < 4; ++i) {
        int seg = w * 4 + i;
        bsrc[i] = w2t + ((size_t)e * H + n0 + seg * 8 + lr8) * F + swc * 8;
    }

    f32x4 acc[2][4] = {};
    int mb = (w >> 1) * 32, nb = (w & 1) * 64;
    int lr = lane & 15, x16 = lane >> 4;
    int sw = (lr & 7) << 4;

    // prologue: stage tile 0
    #pragma unroll
    for (int i = 0; i < 2; ++i) gl_lds16(asrc[i], &Al[0][(w * 2 + i) * 512]);
    #pragma unroll
    for (int i = 0; i < 4; ++i) gl_lds16(bsrc[i], &Bl[0][(w * 4 + i) * 512]);
    __syncthreads();

    int cur = 0;
    for (int t = 0; t < 32; ++t) {
        if (t < 31) {
            int k0 = (t + 1) * 64;
            #pragma unroll
            for (int i = 0; i < 2; ++i) gl_lds16(asrc[i] + k0, &Al[cur ^ 1][(w * 2 + i) * 512]);
            #pragma unroll
            for (int i = 0; i < 4; ++i) gl_lds16(bsrc[i] + k0, &Bl[cur ^ 1][(w * 4 + i) * 512]);
        }
        #pragma unroll
        for (int kk = 0; kk < 2; ++kk) {
            int co = (kk * 64 + x16 * 16) ^ sw;
            bf16x8 a[2], b[4];
            #pragma unroll
            for (int i = 0; i < 2; ++i)
                a[i] = *(const bf16x8*)((const char*)Al[cur] + (mb + i * 16 + lr) * 128 + co);
            #pragma unroll
            for (int j = 0; j < 4; ++j)
                b[j] = *(const bf16x8*)((const char*)Bl[cur] + (nb + j * 16 + lr) * 128 + co);
            #pragma unroll
            for (int i = 0; i < 2; ++i)
                #pragma unroll
                for (int j = 0; j < 4; ++j)
                    acc[i][j] = __builtin_amdgcn_mfma_f32_16x16x32_bf16(a[i], b[j], acc[i][j], 0, 0, 0);
        }
        __syncthreads();
        cur ^= 1;
    }

    int rbase = x16 * 4;
    #pragma unroll
    for (int j = 0; j < 4; ++j) {
        int gcol = n0 + nb + j * 16 + lr;
        float bias = b2[e * H + gcol];
        #pragma unroll
        for (int i = 0; i < 2; ++i) {
            #pragma unroll
            for (int r = 0; r < 4; ++r) {
                int rl = mb + i * 16 + rbase + r;
                int p = m0 + rl;
                if (p < segEnd) {
                    out[(size_t)stokL[rl] * H + gcol] = gsL[rl] * (acc[i][j][r] + bias);
                }
            }
        }
    }
}

extern "C" void kernel_launch(void* const* d_in, const int* in_sizes, int n_in,
                              void* d_out, int out_size, void* d_ws, size_t ws_size,
                              hipStream_t stream) {
    const float* x  = (const float*)d_in[0];
    const float* Wg = (const float*)d_in[1];
    const float* W1 = (const float*)d_in[2];
    const float* b1 = (const float*)d_in[3];
    const float* W2 = (const float*)d_in[4];
    const float* b2 = (const float*)d_in[5];
    float* out = (float*)d_out;

    char* ws = (char*)d_ws;
    unsigned short* xg  = (unsigned short*)(ws + 0);          //  8 MB
    unsigned short* w1t = (unsigned short*)(ws + 8388608);    // 16 MB
    unsigned short* w2t = (unsigned short*)(ws + 25165824);   // 16 MB
    unsigned short* hbf = (unsigned short*)(ws + 41943040);   // 32 MB
    float* gate = (float*)(ws + 75497472);                    // 32 KB
    float* gs   = (float*)(ws + 75530240);                    // 32 KB
    int* stok   = (int*)(ws + 75563008);                      // 32 KB
    int* list   = (int*)(ws + 75595776);                      // 128 KB
    int* cnt    = (int*)(ws + 75726848);                      // 64 B
    int* ebase  = (int*)(ws + 75726912);                      // 64 B
    float* pprob= (float*)(ws + 75726976);                    // 8 KB
    int* work1  = (int*)(ws + 75735168);                      // 512 B
    int* work2  = (int*)(ws + 75735680);                      // 1 KB
    int* nwork  = (int*)(ws + 75736704);                      // 64 B

    hipMemsetAsync(cnt, 0, 8 * sizeof(int), stream);
    transpose_cvt_kernel<<<dim3(32, 8, 8), 256, 0, stream>>>(W1, w1t, 512, 2048);
    transpose_cvt_kernel<<<dim3(8, 32, 8), 256, 0, stream>>>(W2, w2t, 2048, 512);
    router_kernel<<<256, 256, 0, stream>>>(x, Wg, gate, list, cnt, pprob);
    plan_kernel<<<1, 64, 0, stream>>>(cnt, pprob, ebase, work1, work2, nwork,
                                      out + (size_t)NTOK * H);
    gather_kernel<<<2048, 256, 0, stream>>>(x, gate, list, ebase, xg, gs, stok);
    gemm1_kernel<<<dim3(16, 72), 256, 0, stream>>>(xg, w1t, b1, ebase, cnt, work1, nwork, hbf);
    gemm2_kernel<<<dim3(4, 136), 256, 0, stream>>>(hbf, w2t, b2, ebase, cnt, work2, nwork,
                                                   gs, stok, out);
}

// Round 5
// 132.068 us; speedup vs baseline: 1.3087x; 1.0464x over previous
//
#include <hip/hip_runtime.h>
#include <hip/hip_bf16.h>
#include <stdint.h>

#define H 512
#define F 2048
#define E 8
#define NTOK 8192
#define LSTRIDE 4096

typedef __bf16 bf16x8 __attribute__((ext_vector_type(8)));
typedef float f32x4 __attribute__((ext_vector_type(4)));

__device__ __forceinline__ unsigned short f2bf(float f) {
    unsigned u = __builtin_bit_cast(unsigned, f);
    u += 0x7FFFu + ((u >> 16) & 1u);
    return (unsigned short)(u >> 16);
}

__device__ __forceinline__ void gl_lds16(const unsigned short* g, unsigned short* l) {
    __builtin_amdgcn_global_load_lds(
        (const __attribute__((address_space(1))) unsigned int*)g,
        (__attribute__((address_space(3))) unsigned int*)l,
        16, 0, 0);
}

// ---------- transpose + convert: src [b][R][C] fp32 -> dst [b][C][R] bf16 ----------
__global__ void transpose_cvt_kernel(const float* __restrict__ src, unsigned short* __restrict__ dst,
                                     int R, int C) {
    __shared__ unsigned short t[64][72];
    const float* s = src + (size_t)blockIdx.z * R * C;
    unsigned short* d = dst + (size_t)blockIdx.z * R * C;
    int r0 = blockIdx.y * 64, c0 = blockIdx.x * 64;
    int tid = threadIdx.x;
    int lrow = tid >> 4, lc4 = (tid & 15) * 4;
    #pragma unroll
    for (int p = 0; p < 4; ++p) {
        int r = p * 16 + lrow;
        float4 v = *(const float4*)(s + (size_t)(r0 + r) * C + c0 + lc4);
        uint2 u;
        u.x = (unsigned)f2bf(v.x) | ((unsigned)f2bf(v.y) << 16);
        u.y = (unsigned)f2bf(v.z) | ((unsigned)f2bf(v.w) << 16);
        *(uint2*)(&t[r][lc4]) = u;
    }
    __syncthreads();
    int och = tid & 7;
    #pragma unroll
    for (int q = 0; q < 2; ++q) {
        int orow = q * 32 + (tid >> 3);
        unsigned short u[8];
        #pragma unroll
        for (int si = 0; si < 8; ++si) u[si] = t[och * 8 + si][orow];
        uint4 uv;
        uv.x = (unsigned)u[0] | ((unsigned)u[1] << 16);
        uv.y = (unsigned)u[2] | ((unsigned)u[3] << 16);
        uv.z = (unsigned)u[4] | ((unsigned)u[5] << 16);
        uv.w = (unsigned)u[6] | ((unsigned)u[7] << 16);
        *(uint4*)(d + (size_t)(c0 + orow) * R + r0 + och * 8) = uv;
    }
}

// ---------- router ----------
__global__ void router_kernel(const float* __restrict__ x, const float* __restrict__ Wg,
                              float* __restrict__ gate, int* __restrict__ list,
                              int* __restrict__ cnt, float* __restrict__ pprob) {
    __shared__ float wg[H * E];
    __shared__ float lg[32][8];
    __shared__ int am_l[32];
    __shared__ int rank_l[32];
    __shared__ int eb[8];
    int tid = threadIdx.x;

    #pragma unroll
    for (int p = 0; p < 16; ++p) wg[p * 256 + tid] = Wg[p * 256 + tid];
    __syncthreads();

    int tl = tid >> 3, e = tid & 7;
    int token = blockIdx.x * 32 + tl;
    const float4* x4 = (const float4*)(x + (size_t)token * H);
    float acc = 0.f;
    for (int kq = 0; kq < 128; ++kq) {
        float4 v = x4[kq];
        acc += v.x * wg[(kq * 4 + 0) * 8 + e];
        acc += v.y * wg[(kq * 4 + 1) * 8 + e];
        acc += v.z * wg[(kq * 4 + 2) * 8 + e];
        acc += v.w * wg[(kq * 4 + 3) * 8 + e];
    }
    lg[tl][e] = acc;
    __syncthreads();

    if (tid < 32) {
        float l[8];
        #pragma unroll
        for (int q = 0; q < 8; ++q) l[q] = lg[tid][q];
        float mx = l[0];
        #pragma unroll
        for (int q = 1; q < 8; ++q) mx = fmaxf(mx, l[q]);
        float p[8]; float s = 0.f;
        #pragma unroll
        for (int q = 0; q < 8; ++q) { p[q] = expf(l[q] - mx); s += p[q]; }
        int am = 0; float best = l[0];
        #pragma unroll
        for (int q = 1; q < 8; ++q) if (l[q] > best) { best = l[q]; am = q; }
        float inv = 1.f / s;
        #pragma unroll
        for (int q = 0; q < 8; ++q) lg[tid][q] = p[q] * inv;
        float sp = p[am] * inv;
        gate[blockIdx.x * 32 + tid] = sp / (sp + 1e-8f);
        am_l[tid] = am;
    }
    __syncthreads();

    if (tid < 8) {
        float s = 0.f;
        for (int i = 0; i < 32; ++i) s += lg[i][tid];
        pprob[blockIdx.x * 8 + tid] = s;
        int c = 0;
        for (int i = 0; i < 32; ++i) if (am_l[i] == tid) rank_l[i] = c++;
        eb[tid] = atomicAdd(&cnt[tid], c);
    }
    __syncthreads();

    if (tid < 32) {
        int e2 = am_l[tid];
        int pos = eb[e2] + rank_l[tid];
        if (pos < LSTRIDE) list[e2 * LSTRIDE + pos] = blockIdx.x * 32 + tid;
    }
}

// ---------- plan: prefix bases + lb loss ----------
__global__ void plan_kernel(const int* __restrict__ cnt, const float* __restrict__ pprob,
                            int* __restrict__ ebase, float* __restrict__ outlb) {
    __shared__ float s[8];
    int t = threadIdx.x;
    if (t < 8) {
        float acc = 0.f;
        for (int i = 0; i < 256; ++i) acc += pprob[i * 8 + t];
        s[t] = acc * (float)cnt[t];
    }
    __syncthreads();
    if (t == 0) {
        float tot = 0.f;
        for (int q = 0; q < 8; ++q) tot += s[q];
        outlb[0] = tot * (8.0f / ((float)NTOK * (float)NTOK));
        int b = 0;
        for (int e = 0; e < E; ++e) { ebase[e] = b; b += cnt[e]; }
    }
}

// ---------- gather: x (fp32, token order) -> xg (bf16, expert-sorted) + gs/stok ----------
__global__ void gather_kernel(const float* __restrict__ x, const float* __restrict__ gate,
                              const int* __restrict__ list, const int* __restrict__ ebase,
                              unsigned short* __restrict__ xg, float* __restrict__ gs,
                              int* __restrict__ stok) {
    int p = blockIdx.x * 4 + (threadIdx.x >> 6);
    int lane = threadIdx.x & 63;
    int e = 0;
    #pragma unroll
    for (int q = 1; q < 8; ++q) if (p >= ebase[q]) e = q;
    int token = list[e * LSTRIDE + (p - ebase[e])];
    const float4* src = (const float4*)(x + (size_t)token * H) + lane * 2;
    float4 a = src[0], b = src[1];
    uint4 u;
    u.x = (unsigned)f2bf(a.x) | ((unsigned)f2bf(a.y) << 16);
    u.y = (unsigned)f2bf(a.z) | ((unsigned)f2bf(a.w) << 16);
    u.z = (unsigned)f2bf(b.x) | ((unsigned)f2bf(b.y) << 16);
    u.w = (unsigned)f2bf(b.z) | ((unsigned)f2bf(b.w) << 16);
    *(uint4*)(xg + (size_t)p * H + lane * 8) = u;
    if (lane == 0) { stok[p] = token; gs[p] = gate[token]; }
}

// ---------- GEMM1: h = relu(xg @ W1t^T + b1), 128x128xBK64, dbuf, XCD=expert ----------
__global__ __launch_bounds__(256, 2) void gemm1_kernel(
    const unsigned short* __restrict__ xg,    // [NTOK][H] sorted
    const unsigned short* __restrict__ w1t,   // [E][F][H]
    const float* __restrict__ b1,
    const int* __restrict__ ebase, const int* __restrict__ cnt,
    unsigned short* __restrict__ hbf)         // [NTOK][F] sorted
{
    int bid = blockIdx.x;
    int e = bid & 7;                 // expert -> XCD
    int idx = bid >> 3;              // 0..255
    int mblk = idx >> 4;             // m-major
    int c = cnt[e];
    if (mblk * 128 >= c) return;
    int n0 = (idx & 15) * 128;       // n fastest -> same-XCD A-tile reuse
    int m0 = ebase[e] + mblk * 128;
    int segEnd = ebase[e] + c;

    __shared__ unsigned short Al[2][128 * 64];   // 2 x 16 KB
    __shared__ unsigned short Bl[2][128 * 64];   // 2 x 16 KB

    int tid = threadIdx.x, lane = tid & 63, w = tid >> 6;
    int lr8 = lane >> 3, lch = lane & 7;
    int swc = lch ^ lr8;                       // source-side chunk swizzle

    const unsigned short* asrc[4];
    const unsigned short* bsrc[4];
    #pragma unroll
    for (int i = 0; i < 4; ++i) {
        int seg = w * 4 + i;
        int row = seg * 8 + lr8;
        int ar = m0 + row; if (ar > NTOK - 1) ar = NTOK - 1;
        asrc[i] = xg + (size_t)ar * H + swc * 8;
        bsrc[i] = w1t + ((size_t)e * F + n0 + row) * H + swc * 8;
    }

    f32x4 acc[4][4] = {};
    int mb = (w >> 1) * 64, nb = (w & 1) * 64;
    int lr = lane & 15, x16 = lane >> 4;
    int sw = (lr & 7) << 4;                    // read-side byte XOR

    // prologue: stage tile 0
    #pragma unroll
    for (int i = 0; i < 4; ++i) {
        gl_lds16(asrc[i], &Al[0][(w * 4 + i) * 512]);
        gl_lds16(bsrc[i], &Bl[0][(w * 4 + i) * 512]);
    }
    __syncthreads();

    int cur = 0;
    for (int t = 0; t < 8; ++t) {
        if (t < 7) {
            int k0 = (t + 1) * 64;
            #pragma unroll
            for (int i = 0; i < 4; ++i) {
                gl_lds16(asrc[i] + k0, &Al[cur ^ 1][(w * 4 + i) * 512]);
                gl_lds16(bsrc[i] + k0, &Bl[cur ^ 1][(w * 4 + i) * 512]);
            }
        }
        #pragma unroll
        for (int kk = 0; kk < 2; ++kk) {
            int co = (kk * 64 + x16 * 16) ^ sw;
            bf16x8 a[4], b[4];
            #pragma unroll
            for (int i = 0; i < 4; ++i)
                a[i] = *(const bf16x8*)((const char*)Al[cur] + (mb + i * 16 + lr) * 128 + co);
            #pragma unroll
            for (int j = 0; j < 4; ++j)
                b[j] = *(const bf16x8*)((const char*)Bl[cur] + (nb + j * 16 + lr) * 128 + co);
            #pragma unroll
            for (int i = 0; i < 4; ++i)
                #pragma unroll
                for (int j = 0; j < 4; ++j)
                    acc[i][j] = __builtin_amdgcn_mfma_f32_16x16x32_bf16(b[j], a[i], acc[i][j], 0, 0, 0);
        }
        __syncthreads();
        cur ^= 1;
    }

    // epilogue: lane holds 4 consecutive F-cols of one token -> 8B packed stores
    int tcol = lane & 15, w4 = x16 * 4;
    #pragma unroll
    for (int j = 0; j < 4; ++j) {
        int gc = n0 + nb + j * 16 + w4;
        float4 bias = *(const float4*)(b1 + e * F + gc);
        #pragma unroll
        for (int i = 0; i < 4; ++i) {
            int p = m0 + mb + i * 16 + tcol;
            if (p < segEnd) {
                float v0 = acc[i][j][0] + bias.x; v0 = v0 > 0.f ? v0 : 0.f;
                float v1 = acc[i][j][1] + bias.y; v1 = v1 > 0.f ? v1 : 0.f;
                float v2 = acc[i][j][2] + bias.z; v2 = v2 > 0.f ? v2 : 0.f;
                float v3 = acc[i][j][3] + bias.w; v3 = v3 > 0.f ? v3 : 0.f;
                uint2 pk;
                pk.x = (unsigned)f2bf(v0) | ((unsigned)f2bf(v1) << 16);
                pk.y = (unsigned)f2bf(v2) | ((unsigned)f2bf(v3) << 16);
                *(uint2*)(hbf + (size_t)p * F + gc) = pk;
            }
        }
    }
}

// ---------- GEMM2: out = gate*(h @ W2t^T + b2) scattered, 64x128xBK64, dbuf, XCD=expert ----------
__global__ __launch_bounds__(256, 3) void gemm2_kernel(
    const unsigned short* __restrict__ hbf,   // [NTOK][F] sorted
    const unsigned short* __restrict__ w2t,   // [E][H][F]
    const float* __restrict__ b2,
    const int* __restrict__ ebase, const int* __restrict__ cnt,
    const float* __restrict__ gs, const int* __restrict__ stok,
    float* __restrict__ out)                  // [NTOK][H] token order
{
    int bid = blockIdx.x;
    int e = bid & 7;
    int idx = bid >> 3;              // 0..127
    int mblk = idx >> 2;             // 0..31
    int c = cnt[e];
    if (mblk * 64 >= c) return;
    int n0 = (idx & 3) * 128;
    int m0 = ebase[e] + mblk * 64;
    int segEnd = ebase[e] + c;

    __shared__ unsigned short Al[2][64 * 64];    // 2 x 8 KB
    __shared__ unsigned short Bl[2][128 * 64];   // 2 x 16 KB
    __shared__ int stokL[64];
    __shared__ float gsL[64];

    int tid = threadIdx.x, lane = tid & 63, w = tid >> 6;
    if (tid < 64) {
        int p = m0 + tid;
        int pc = p > NTOK - 1 ? NTOK - 1 : p;
        stokL[tid] = stok[pc];
        gsL[tid] = gs[pc];
    }
    int lr8 = lane >> 3, lch = lane & 7;
    int swc = lch ^ lr8;

    const unsigned short* asrc[2];
    const unsigned short* bsrc[4];
    #pragma unroll
    for (int i = 0; i < 2; ++i) {
        int row = (w * 2 + i) * 8 + lr8;
        int ar = m0 + row; if (ar > NTOK - 1) ar = NTOK - 1;
        asrc[i] = hbf + (size_t)ar * F + swc * 8;
    }
    #pragma unroll
    for (int i = 0; i < 4; ++i) {
        int row = (w * 4 + i) * 8 + lr8;
        bsrc[i] = w2t + ((size_t)e * H + n0 + row) * F + swc * 8;
    }

    f32x4 acc[2][4] = {};
    int mb = (w >> 1) * 32, nb = (w & 1) * 64;
    int lr = lane & 15, x16 = lane >> 4;
    int sw = (lr & 7) << 4;

    // prologue
    #pragma unroll
    for (int i = 0; i < 2; ++i) gl_lds16(asrc[i], &Al[0][(w * 2 + i) * 512]);
    #pragma unroll
    for (int i = 0; i < 4; ++i) gl_lds16(bsrc[i], &Bl[0][(w * 4 + i) * 512]);
    __syncthreads();

    int cur = 0;
    for (int t = 0; t < 32; ++t) {
        if (t < 31) {
            int k0 = (t + 1) * 64;
            #pragma unroll
            for (int i = 0; i < 2; ++i) gl_lds16(asrc[i] + k0, &Al[cur ^ 1][(w * 2 + i) * 512]);
            #pragma unroll
            for (int i = 0; i < 4; ++i) gl_lds16(bsrc[i] + k0, &Bl[cur ^ 1][(w * 4 + i) * 512]);
        }
        #pragma unroll
        for (int kk = 0; kk < 2; ++kk) {
            int co = (kk * 64 + x16 * 16) ^ sw;
            bf16x8 a[2], b[4];
            #pragma unroll
            for (int i = 0; i < 2; ++i)
                a[i] = *(const bf16x8*)((const char*)Al[cur] + (mb + i * 16 + lr) * 128 + co);
            #pragma unroll
            for (int j = 0; j < 4; ++j)
                b[j] = *(const bf16x8*)((const char*)Bl[cur] + (nb + j * 16 + lr) * 128 + co);
            #pragma unroll
            for (int i = 0; i < 2; ++i)
                #pragma unroll
                for (int j = 0; j < 4; ++j)
                    acc[i][j] = __builtin_amdgcn_mfma_f32_16x16x32_bf16(b[j], a[i], acc[i][j], 0, 0, 0);
        }
        __syncthreads();
        cur ^= 1;
    }

    // epilogue: lane holds 4 consecutive H-cols of one token -> float4 stores
    int tcol = lane & 15, w4 = x16 * 4;
    #pragma unroll
    for (int i = 0; i < 2; ++i) {
        int rl = mb + i * 16 + tcol;
        int p = m0 + rl;
        if (p < segEnd) {
            int tok = stokL[rl];
            float g = gsL[rl];
            #pragma unroll
            for (int j = 0; j < 4; ++j) {
                int gc = n0 + nb + j * 16 + w4;
                float4 bias = *(const float4*)(b2 + e * H + gc);
                float4 res;
                res.x = g * (acc[i][j][0] + bias.x);
                res.y = g * (acc[i][j][1] + bias.y);
                res.z = g * (acc[i][j][2] + bias.z);
                res.w = g * (acc[i][j][3] + bias.w);
                *(float4*)(out + (size_t)tok * H + gc) = res;
            }
        }
    }
}

extern "C" void kernel_launch(void* const* d_in, const int* in_sizes, int n_in,
                              void* d_out, int out_size, void* d_ws, size_t ws_size,
                              hipStream_t stream) {
    const float* x  = (const float*)d_in[0];
    const float* Wg = (const float*)d_in[1];
    const float* W1 = (const float*)d_in[2];
    const float* b1 = (const float*)d_in[3];
    const float* W2 = (const float*)d_in[4];
    const float* b2 = (const float*)d_in[5];
    float* out = (float*)d_out;

    char* ws = (char*)d_ws;
    unsigned short* xg  = (unsigned short*)(ws + 0);          //  8 MB
    unsigned short* w1t = (unsigned short*)(ws + 8388608);    // 16 MB
    unsigned short* w2t = (unsigned short*)(ws + 25165824);   // 16 MB
    unsigned short* hbf = (unsigned short*)(ws + 41943040);   // 32 MB
    float* gate = (float*)(ws + 75497472);                    // 32 KB
    float* gs   = (float*)(ws + 75530240);                    // 32 KB
    int* stok   = (int*)(ws + 75563008);                      // 32 KB
    int* list   = (int*)(ws + 75595776);                      // 128 KB
    int* cnt    = (int*)(ws + 75726848);                      // 64 B
    int* ebase  = (int*)(ws + 75726912);                      // 64 B
    float* pprob= (float*)(ws + 75726976);                    // 8 KB

    hipMemsetAsync(cnt, 0, 8 * sizeof(int), stream);
    transpose_cvt_kernel<<<dim3(32, 8, 8), 256, 0, stream>>>(W1, w1t, 512, 2048);
    transpose_cvt_kernel<<<dim3(8, 32, 8), 256, 0, stream>>>(W2, w2t, 2048, 512);
    router_kernel<<<256, 256, 0, stream>>>(x, Wg, gate, list, cnt, pprob);
    plan_kernel<<<1, 64, 0, stream>>>(cnt, pprob, ebase, out + (size_t)NTOK * H);
    gather_kernel<<<2048, 256, 0, stream>>>(x, gate, list, ebase, xg, gs, stok);
    gemm1_kernel<<<2048, 256, 0, stream>>>(xg, w1t, b1, ebase, cnt, hbf);
    gemm2_kernel<<<1024, 256, 0, stream>>>(hbf, w2t, b2, ebase, cnt, gs, stok, out);
}

// Round 6
// 124.459 us; speedup vs baseline: 1.3887x; 1.0611x over previous
//
#include <hip/hip_runtime.h>
#include <hip/hip_bf16.h>
#include <stdint.h>

#define H 512
#define F 2048
#define E 8
#define NTOK 8192
#define LSTRIDE 4096

typedef __bf16 bf16x8 __attribute__((ext_vector_type(8)));
typedef float f32x4 __attribute__((ext_vector_type(4)));

__device__ __forceinline__ unsigned short f2bf(float f) {
    unsigned u = __builtin_bit_cast(unsigned, f);
    u += 0x7FFFu + ((u >> 16) & 1u);
    return (unsigned short)(u >> 16);
}

__device__ __forceinline__ void gl_lds16(const unsigned short* g, unsigned short* l) {
    __builtin_amdgcn_global_load_lds(
        (const __attribute__((address_space(1))) unsigned int*)g,
        (__attribute__((address_space(3))) unsigned int*)l,
        16, 0, 0);
}

// ---------- transpose + convert: src [b][R][C] fp32 -> dst [b][C][R] bf16 ----------
__global__ void transpose_cvt_kernel(const float* __restrict__ src, unsigned short* __restrict__ dst,
                                     int R, int C) {
    __shared__ unsigned short t[64][72];
    const float* s = src + (size_t)blockIdx.z * R * C;
    unsigned short* d = dst + (size_t)blockIdx.z * R * C;
    int r0 = blockIdx.y * 64, c0 = blockIdx.x * 64;
    int tid = threadIdx.x;
    int lrow = tid >> 4, lc4 = (tid & 15) * 4;
    #pragma unroll
    for (int p = 0; p < 4; ++p) {
        int r = p * 16 + lrow;
        float4 v = *(const float4*)(s + (size_t)(r0 + r) * C + c0 + lc4);
        uint2 u;
        u.x = (unsigned)f2bf(v.x) | ((unsigned)f2bf(v.y) << 16);
        u.y = (unsigned)f2bf(v.z) | ((unsigned)f2bf(v.w) << 16);
        *(uint2*)(&t[r][lc4]) = u;
    }
    __syncthreads();
    int och = tid & 7;
    #pragma unroll
    for (int q = 0; q < 2; ++q) {
        int orow = q * 32 + (tid >> 3);
        unsigned short u[8];
        #pragma unroll
        for (int si = 0; si < 8; ++si) u[si] = t[och * 8 + si][orow];
        uint4 uv;
        uv.x = (unsigned)u[0] | ((unsigned)u[1] << 16);
        uv.y = (unsigned)u[2] | ((unsigned)u[3] << 16);
        uv.z = (unsigned)u[4] | ((unsigned)u[5] << 16);
        uv.w = (unsigned)u[6] | ((unsigned)u[7] << 16);
        *(uint4*)(d + (size_t)(c0 + orow) * R + r0 + och * 8) = uv;
    }
}

// ---------- router ----------
__global__ void router_kernel(const float* __restrict__ x, const float* __restrict__ Wg,
                              float* __restrict__ gate, int* __restrict__ list,
                              int* __restrict__ cnt, float* __restrict__ pprob) {
    __shared__ float wg[H * E];
    __shared__ float lg[32][8];
    __shared__ int am_l[32];
    __shared__ int rank_l[32];
    __shared__ int eb[8];
    int tid = threadIdx.x;

    #pragma unroll
    for (int p = 0; p < 16; ++p) wg[p * 256 + tid] = Wg[p * 256 + tid];
    __syncthreads();

    int tl = tid >> 3, e = tid & 7;
    int token = blockIdx.x * 32 + tl;
    const float4* x4 = (const float4*)(x + (size_t)token * H);
    float acc = 0.f;
    for (int kq = 0; kq < 128; ++kq) {
        float4 v = x4[kq];
        acc += v.x * wg[(kq * 4 + 0) * 8 + e];
        acc += v.y * wg[(kq * 4 + 1) * 8 + e];
        acc += v.z * wg[(kq * 4 + 2) * 8 + e];
        acc += v.w * wg[(kq * 4 + 3) * 8 + e];
    }
    lg[tl][e] = acc;
    __syncthreads();

    if (tid < 32) {
        float l[8];
        #pragma unroll
        for (int q = 0; q < 8; ++q) l[q] = lg[tid][q];
        float mx = l[0];
        #pragma unroll
        for (int q = 1; q < 8; ++q) mx = fmaxf(mx, l[q]);
        float p[8]; float s = 0.f;
        #pragma unroll
        for (int q = 0; q < 8; ++q) { p[q] = expf(l[q] - mx); s += p[q]; }
        int am = 0; float best = l[0];
        #pragma unroll
        for (int q = 1; q < 8; ++q) if (l[q] > best) { best = l[q]; am = q; }
        float inv = 1.f / s;
        #pragma unroll
        for (int q = 0; q < 8; ++q) lg[tid][q] = p[q] * inv;
        float sp = p[am] * inv;
        gate[blockIdx.x * 32 + tid] = sp / (sp + 1e-8f);
        am_l[tid] = am;
    }
    __syncthreads();

    if (tid < 8) {
        float s = 0.f;
        for (int i = 0; i < 32; ++i) s += lg[i][tid];
        pprob[blockIdx.x * 8 + tid] = s;
        int c = 0;
        for (int i = 0; i < 32; ++i) if (am_l[i] == tid) rank_l[i] = c++;
        eb[tid] = atomicAdd(&cnt[tid], c);
    }
    __syncthreads();

    if (tid < 32) {
        int e2 = am_l[tid];
        int pos = eb[e2] + rank_l[tid];
        if (pos < LSTRIDE) list[e2 * LSTRIDE + pos] = blockIdx.x * 32 + tid;
    }
}

// ---------- plan: prefix bases + lb loss ----------
__global__ void plan_kernel(const int* __restrict__ cnt, const float* __restrict__ pprob,
                            int* __restrict__ ebase, float* __restrict__ outlb) {
    __shared__ float s[8];
    int t = threadIdx.x;
    if (t < 8) {
        float acc = 0.f;
        for (int i = 0; i < 256; ++i) acc += pprob[i * 8 + t];
        s[t] = acc * (float)cnt[t];
    }
    __syncthreads();
    if (t == 0) {
        float tot = 0.f;
        for (int q = 0; q < 8; ++q) tot += s[q];
        outlb[0] = tot * (8.0f / ((float)NTOK * (float)NTOK));
        int b = 0;
        for (int e = 0; e < E; ++e) { ebase[e] = b; b += cnt[e]; }
    }
}

// ---------- gather: x (fp32, token order) -> xg (bf16, expert-sorted) + gs/stok ----------
__global__ void gather_kernel(const float* __restrict__ x, const float* __restrict__ gate,
                              const int* __restrict__ list, const int* __restrict__ ebase,
                              unsigned short* __restrict__ xg, float* __restrict__ gs,
                              int* __restrict__ stok) {
    int p = blockIdx.x * 4 + (threadIdx.x >> 6);
    int lane = threadIdx.x & 63;
    int e = 0;
    #pragma unroll
    for (int q = 1; q < 8; ++q) if (p >= ebase[q]) e = q;
    int token = list[e * LSTRIDE + (p - ebase[e])];
    const float4* src = (const float4*)(x + (size_t)token * H) + lane * 2;
    float4 a = src[0], b = src[1];
    uint4 u;
    u.x = (unsigned)f2bf(a.x) | ((unsigned)f2bf(a.y) << 16);
    u.y = (unsigned)f2bf(a.z) | ((unsigned)f2bf(a.w) << 16);
    u.z = (unsigned)f2bf(b.x) | ((unsigned)f2bf(b.y) << 16);
    u.w = (unsigned)f2bf(b.z) | ((unsigned)f2bf(b.w) << 16);
    *(uint4*)(xg + (size_t)p * H + lane * 8) = u;
    if (lane == 0) { stok[p] = token; gs[p] = gate[token]; }
}

// ---------- GEMM1: h = relu(xg @ W1t^T + b1), 128x128xBK64, counted-vmcnt dbuf ----------
__global__ __launch_bounds__(256, 2) void gemm1_kernel(
    const unsigned short* __restrict__ xg,    // [NTOK][H] sorted
    const unsigned short* __restrict__ w1t,   // [E][F][H]
    const float* __restrict__ b1,
    const int* __restrict__ ebase, const int* __restrict__ cnt,
    unsigned short* __restrict__ hbf)         // [NTOK][F] sorted
{
    int bid = blockIdx.x;
    int e = bid & 7;                 // expert -> XCD
    int idx = bid >> 3;              // 0..511
    int mblk = idx >> 4;             // m-major (0..31)
    int c = cnt[e];
    if (mblk * 128 >= c) return;
    int n0 = (idx & 15) * 128;       // n fastest -> same-XCD A-tile reuse
    int m0 = ebase[e] + mblk * 128;
    int segEnd = ebase[e] + c;

    __shared__ unsigned short Al[2][128 * 64];   // 2 x 16 KB
    __shared__ unsigned short Bl[2][128 * 64];   // 2 x 16 KB

    int tid = threadIdx.x, lane = tid & 63, w = tid >> 6;
    int lr8 = lane >> 3, lch = lane & 7;
    int swc = lch ^ lr8;                       // source-side chunk swizzle

    const unsigned short* asrc[4];
    const unsigned short* bsrc[4];
    #pragma unroll
    for (int i = 0; i < 4; ++i) {
        int seg = w * 4 + i;
        int row = seg * 8 + lr8;
        int ar = m0 + row; if (ar > NTOK - 1) ar = NTOK - 1;
        asrc[i] = xg + (size_t)ar * H + swc * 8;
        bsrc[i] = w1t + ((size_t)e * F + n0 + row) * H + swc * 8;
    }

    f32x4 acc[4][4] = {};
    int mb = (w >> 1) * 64, nb = (w & 1) * 64;
    int lr = lane & 15, x16 = lane >> 4;
    int sw = (lr & 7) << 4;                    // read-side byte XOR

    // prologue: stage tile 0 into buf 0 (8 loads/thread in flight)
    #pragma unroll
    for (int i = 0; i < 4; ++i) {
        gl_lds16(asrc[i], &Al[0][(w * 4 + i) * 512]);
        gl_lds16(bsrc[i], &Bl[0][(w * 4 + i) * 512]);
    }

    int cur = 0;
    #pragma unroll
    for (int t = 0; t < 8; ++t) {
        if (t < 7) {
            int k0 = (t + 1) * 64;
            #pragma unroll
            for (int i = 0; i < 4; ++i) {
                gl_lds16(asrc[i] + k0, &Al[cur ^ 1][(w * 4 + i) * 512]);
                gl_lds16(bsrc[i] + k0, &Bl[cur ^ 1][(w * 4 + i) * 512]);
            }
            asm volatile("s_waitcnt vmcnt(8)" ::: "memory");  // tile t landed; t+1 in flight
        } else {
            asm volatile("s_waitcnt vmcnt(0)" ::: "memory");
        }
        __builtin_amdgcn_s_barrier();          // all waves' tile-t loads visible
        #pragma unroll
        for (int kk = 0; kk < 2; ++kk) {
            int co = (kk * 64 + x16 * 16) ^ sw;
            bf16x8 a[4], b[4];
            #pragma unroll
            for (int i = 0; i < 4; ++i)
                a[i] = *(const bf16x8*)((const char*)Al[cur] + (mb + i * 16 + lr) * 128 + co);
            #pragma unroll
            for (int j = 0; j < 4; ++j)
                b[j] = *(const bf16x8*)((const char*)Bl[cur] + (nb + j * 16 + lr) * 128 + co);
            #pragma unroll
            for (int i = 0; i < 4; ++i)
                #pragma unroll
                for (int j = 0; j < 4; ++j)
                    acc[i][j] = __builtin_amdgcn_mfma_f32_16x16x32_bf16(b[j], a[i], acc[i][j], 0, 0, 0);
        }
        asm volatile("s_waitcnt lgkmcnt(0)" ::: "memory");    // done reading buf[cur]
        __builtin_amdgcn_s_barrier();          // before next iter overwrites it
        cur ^= 1;
    }

    // epilogue: lane holds 4 consecutive F-cols of one token -> 8B packed stores
    int tcol = lane & 15, w4 = x16 * 4;
    #pragma unroll
    for (int j = 0; j < 4; ++j) {
        int gc = n0 + nb + j * 16 + w4;
        float4 bias = *(const float4*)(b1 + e * F + gc);
        #pragma unroll
        for (int i = 0; i < 4; ++i) {
            int p = m0 + mb + i * 16 + tcol;
            if (p < segEnd) {
                float v0 = acc[i][j][0] + bias.x; v0 = v0 > 0.f ? v0 : 0.f;
                float v1 = acc[i][j][1] + bias.y; v1 = v1 > 0.f ? v1 : 0.f;
                float v2 = acc[i][j][2] + bias.z; v2 = v2 > 0.f ? v2 : 0.f;
                float v3 = acc[i][j][3] + bias.w; v3 = v3 > 0.f ? v3 : 0.f;
                uint2 pk;
                pk.x = (unsigned)f2bf(v0) | ((unsigned)f2bf(v1) << 16);
                pk.y = (unsigned)f2bf(v2) | ((unsigned)f2bf(v3) << 16);
                *(uint2*)(hbf + (size_t)p * F + gc) = pk;
            }
        }
    }
}

// ---------- GEMM2: out = gate*(h @ W2t^T + b2) scattered, 128x128xBK64, counted-vmcnt dbuf ----------
__global__ __launch_bounds__(256, 2) void gemm2_kernel(
    const unsigned short* __restrict__ hbf,   // [NTOK][F] sorted
    const unsigned short* __restrict__ w2t,   // [E][H][F]
    const float* __restrict__ b2,
    const int* __restrict__ ebase, const int* __restrict__ cnt,
    const float* __restrict__ gs, const int* __restrict__ stok,
    float* __restrict__ out)                  // [NTOK][H] token order
{
    int bid = blockIdx.x;
    int e = bid & 7;
    int idx = bid >> 3;              // 0..127
    int mblk = idx >> 2;             // 0..31
    int c = cnt[e];
    if (mblk * 128 >= c) return;
    int n0 = (idx & 3) * 128;
    int m0 = ebase[e] + mblk * 128;
    int segEnd = ebase[e] + c;

    __shared__ unsigned short Al[2][128 * 64];   // 2 x 16 KB
    __shared__ unsigned short Bl[2][128 * 64];   // 2 x 16 KB
    __shared__ int stokL[128];
    __shared__ float gsL[128];

    int tid = threadIdx.x, lane = tid & 63, w = tid >> 6;
    if (tid < 128) {
        int p = m0 + tid;
        int pc = p > NTOK - 1 ? NTOK - 1 : p;
        stokL[tid] = stok[pc];
        gsL[tid] = gs[pc];
    }
    int lr8 = lane >> 3, lch = lane & 7;
    int swc = lch ^ lr8;

    const unsigned short* asrc[4];
    const unsigned short* bsrc[4];
    #pragma unroll
    for (int i = 0; i < 4; ++i) {
        int row = (w * 4 + i) * 8 + lr8;
        int ar = m0 + row; if (ar > NTOK - 1) ar = NTOK - 1;
        asrc[i] = hbf + (size_t)ar * F + swc * 8;
        bsrc[i] = w2t + ((size_t)e * H + n0 + row) * F + swc * 8;
    }

    f32x4 acc[4][4] = {};
    int mb = (w >> 1) * 64, nb = (w & 1) * 64;
    int lr = lane & 15, x16 = lane >> 4;
    int sw = (lr & 7) << 4;

    // prologue
    #pragma unroll
    for (int i = 0; i < 4; ++i) {
        gl_lds16(asrc[i], &Al[0][(w * 4 + i) * 512]);
        gl_lds16(bsrc[i], &Bl[0][(w * 4 + i) * 512]);
    }
    __builtin_amdgcn_s_barrier();   // toks/gs LDS write visibility (cheap, once)

    int cur = 0;
    #pragma unroll
    for (int t = 0; t < 32; ++t) {
        if (t < 31) {
            int k0 = (t + 1) * 64;
            #pragma unroll
            for (int i = 0; i < 4; ++i) {
                gl_lds16(asrc[i] + k0, &Al[cur ^ 1][(w * 4 + i) * 512]);
                gl_lds16(bsrc[i] + k0, &Bl[cur ^ 1][(w * 4 + i) * 512]);
            }
            asm volatile("s_waitcnt vmcnt(8)" ::: "memory");
        } else {
            asm volatile("s_waitcnt vmcnt(0)" ::: "memory");
        }
        __builtin_amdgcn_s_barrier();
        #pragma unroll
        for (int kk = 0; kk < 2; ++kk) {
            int co = (kk * 64 + x16 * 16) ^ sw;
            bf16x8 a[4], b[4];
            #pragma unroll
            for (int i = 0; i < 4; ++i)
                a[i] = *(const bf16x8*)((const char*)Al[cur] + (mb + i * 16 + lr) * 128 + co);
            #pragma unroll
            for (int j = 0; j < 4; ++j)
                b[j] = *(const bf16x8*)((const char*)Bl[cur] + (nb + j * 16 + lr) * 128 + co);
            #pragma unroll
            for (int i = 0; i < 4; ++i)
                #pragma unroll
                for (int j = 0; j < 4; ++j)
                    acc[i][j] = __builtin_amdgcn_mfma_f32_16x16x32_bf16(b[j], a[i], acc[i][j], 0, 0, 0);
        }
        asm volatile("s_waitcnt lgkmcnt(0)" ::: "memory");
        __builtin_amdgcn_s_barrier();
        cur ^= 1;
    }

    // epilogue: lane holds 4 consecutive H-cols of one token -> float4 stores
    int tcol = lane & 15, w4 = x16 * 4;
    #pragma unroll
    for (int i = 0; i < 4; ++i) {
        int rl = mb + i * 16 + tcol;
        int p = m0 + rl;
        if (p < segEnd) {
            int tok = stokL[rl];
            float g = gsL[rl];
            #pragma unroll
            for (int j = 0; j < 4; ++j) {
                int gc = n0 + nb + j * 16 + w4;
                float4 bias = *(const float4*)(b2 + e * H + gc);
                float4 res;
                res.x = g * (acc[i][j][0] + bias.x);
                res.y = g * (acc[i][j][1] + bias.y);
                res.z = g * (acc[i][j][2] + bias.z);
                res.w = g * (acc[i][j][3] + bias.w);
                *(float4*)(out + (size_t)tok * H + gc) = res;
            }
        }
    }
}

extern "C" void kernel_launch(void* const* d_in, const int* in_sizes, int n_in,
                              void* d_out, int out_size, void* d_ws, size_t ws_size,
                              hipStream_t stream) {
    const float* x  = (const float*)d_in[0];
    const float* Wg = (const float*)d_in[1];
    const float* W1 = (const float*)d_in[2];
    const float* b1 = (const float*)d_in[3];
    const float* W2 = (const float*)d_in[4];
    const float* b2 = (const float*)d_in[5];
    float* out = (float*)d_out;

    char* ws = (char*)d_ws;
    unsigned short* xg  = (unsigned short*)(ws + 0);          //  8 MB
    unsigned short* w1t = (unsigned short*)(ws + 8388608);    // 16 MB
    unsigned short* w2t = (unsigned short*)(ws + 25165824);   // 16 MB
    unsigned short* hbf = (unsigned short*)(ws + 41943040);   // 32 MB
    float* gate = (float*)(ws + 75497472);                    // 32 KB
    float* gs   = (float*)(ws + 75530240);                    // 32 KB
    int* stok   = (int*)(ws + 75563008);                      // 32 KB
    int* list   = (int*)(ws + 75595776);                      // 128 KB
    int* cnt    = (int*)(ws + 75726848);                      // 64 B
    int* ebase  = (int*)(ws + 75726912);                      // 64 B
    float* pprob= (float*)(ws + 75726976);                    // 8 KB

    hipMemsetAsync(cnt, 0, 8 * sizeof(int), stream);
    transpose_cvt_kernel<<<dim3(32, 8, 8), 256, 0, stream>>>(W1, w1t, 512, 2048);
    transpose_cvt_kernel<<<dim3(8, 32, 8), 256, 0, stream>>>(W2, w2t, 2048, 512);
    router_kernel<<<256, 256, 0, stream>>>(x, Wg, gate, list, cnt, pprob);
    plan_kernel<<<1, 64, 0, stream>>>(cnt, pprob, ebase, out + (size_t)NTOK * H);
    gather_kernel<<<2048, 256, 0, stream>>>(x, gate, list, ebase, xg, gs, stok);
    gemm1_kernel<<<4096, 256, 0, stream>>>(xg, w1t, b1, ebase, cnt, hbf);
    gemm2_kernel<<<1024, 256, 0, stream>>>(hbf, w2t, b2, ebase, cnt, gs, stok, out);
}